// Round 3
// baseline (442.687 us; speedup 1.0000x reference)
//
#include <hip/hip_runtime.h>
#include <hip/hip_bf16.h>

typedef unsigned int u32;
typedef unsigned short u16;
typedef __attribute__((ext_vector_type(8))) short short8;   // 8 bf16 (4 VGPRs), MFMA A/B frag
typedef __attribute__((ext_vector_type(4))) float f32x4;    // MFMA C/D frag

#define NEG_SCORE (-100000.0f)

// ---------- bf16 helpers (raw u16 representation) ----------
__device__ __forceinline__ float bflo(u32 u) { return __uint_as_float(u << 16); }
__device__ __forceinline__ float bfhi(u32 u) { return __uint_as_float(u & 0xffff0000u); }
__device__ __forceinline__ u16 f2bf(float f) {
    u32 u = __float_as_uint(f);
    u32 r = (u + 0x7fffu + ((u >> 16) & 1u)) >> 16;   // round-to-nearest-even
    return (u16)r;
}

// ---------- async global->LDS 16B copy ----------
__device__ __forceinline__ void async16(const u16* g, u16* l) {
    __builtin_amdgcn_global_load_lds(
        (const __attribute__((address_space(1))) u32*)g,
        (__attribute__((address_space(3))) u32*)l,
        16, 0, 0);
}

// =====================================================================
// fp32 -> bf16 bulk convert. Each thread converts 8 elements (n % 8 == 0).
// =====================================================================
__global__ __launch_bounds__(256) void f32_to_bf16_kernel(
    const float* __restrict__ src, u16* __restrict__ dst)
{
    const int i = blockIdx.x * 256 + threadIdx.x;
    const float4* s4 = (const float4*)src;
    float4 a = s4[2 * i + 0];
    float4 b = s4[2 * i + 1];
    uint4 o;
    o.x = (u32)f2bf(a.x) | ((u32)f2bf(a.y) << 16);
    o.y = (u32)f2bf(a.z) | ((u32)f2bf(a.w) << 16);
    o.z = (u32)f2bf(b.x) | ((u32)f2bf(b.y) << 16);
    o.w = (u32)f2bf(b.z) | ((u32)f2bf(b.w) << 16);
    ((uint4*)dst)[i] = o;
}

// =====================================================================
// GEMM: C(M,N) = A(M,K) * Bt(N,K)^T + bias(N); bf16 A/B, fp32 bias/accum.
// OUT_BF16 selects bf16 or fp32 C. Requires M%128==0, N%128==0, K%32==0.
// m97-style: 128x128 tile, BK=32, 256 threads = 4 waves, each wave 64x64.
// =====================================================================
template <bool OUT_BF16>
__global__ __launch_bounds__(256) void gemm_bt_bias(
    const u16* __restrict__ A, const u16* __restrict__ Bt,
    const float* __restrict__ bias, void* __restrict__ Cv,
    int M, int N, int K)
{
    __shared__ u16 sA[128 * 32];   // 8 KB, row-major 128 rows x 32 cols
    __shared__ u16 sB[128 * 32];

    const int t    = threadIdx.x;
    const int m0   = blockIdx.y * 128;
    const int n0   = blockIdx.x * 128;
    const int lane = t & 63;
    const int wv   = t >> 6;
    const int wm   = (wv & 1) * 64;
    const int wn   = (wv >> 1) * 64;
    const int lr   = lane & 15;
    const int quad = lane >> 4;

    const u16* pa = A  + (size_t)(m0 + (t >> 2)) * K + ((t & 3) << 3);
    const u16* pb = Bt + (size_t)(n0 + (t >> 2)) * K + ((t & 3) << 3);
    u16* la = &sA[t * 8];
    u16* lb = &sB[t * 8];
    const size_t half = (size_t)64 * K;

    const f32x4 zero4 = {0.f, 0.f, 0.f, 0.f};
    f32x4 acc[4][4];
#pragma unroll
    for (int mt = 0; mt < 4; mt++)
#pragma unroll
        for (int nt = 0; nt < 4; nt++) acc[mt][nt] = zero4;

    for (int kk = 0; kk < K; kk += 32) {
        async16(pa + kk, la);
        async16(pa + kk + half, la + 2048);
        async16(pb + kk, lb);
        async16(pb + kk + half, lb + 2048);
        __syncthreads();   // compiler drains vmcnt before s_barrier

        short8 af[4], bfr[4];
#pragma unroll
        for (int mt = 0; mt < 4; mt++)
            af[mt] = *(const short8*)&sA[(wm + mt * 16 + lr) * 32 + quad * 8];
#pragma unroll
        for (int nt = 0; nt < 4; nt++)
            bfr[nt] = *(const short8*)&sB[(wn + nt * 16 + lr) * 32 + quad * 8];

#pragma unroll
        for (int mt = 0; mt < 4; mt++)
#pragma unroll
            for (int nt = 0; nt < 4; nt++)
                acc[mt][nt] = __builtin_amdgcn_mfma_f32_16x16x32_bf16(
                    af[mt], bfr[nt], acc[mt][nt], 0, 0, 0);
        __syncthreads();
    }

    float bv[4];
#pragma unroll
    for (int nt = 0; nt < 4; nt++)
        bv[nt] = bias[n0 + wn + nt * 16 + lr];

    // D layout: lane holds D[m = quad*4+i][n = lane&15] for i=0..3
#pragma unroll
    for (int mt = 0; mt < 4; mt++) {
#pragma unroll
        for (int i = 0; i < 4; i++) {
            size_t row = (size_t)(m0 + wm + mt * 16 + quad * 4 + i);
#pragma unroll
            for (int nt = 0; nt < 4; nt++) {
                float v = acc[mt][nt][i] + bv[nt];
                size_t idx = row * N + n0 + wn + nt * 16 + lr;
                if (OUT_BF16) ((u16*)Cv)[idx] = f2bf(v);
                else          ((float*)Cv)[idx] = v;
            }
        }
    }
}

// =====================================================================
// Sliding-window attention, ONE WAVE PER (b,h,query).
// qkv row (b*L+l)*3072, head h at cols [h*192, h*192+192): q|k|v 64/64/64.
// Lane p computes the score for window position p (pos = q-32+p); lane 0
// additionally covers p=64. Butterfly shuffle reduce for max/denominator,
// normalized weights in per-wave LDS, then lane d accumulates output dim d
// (V loads coalesced). values layout: (b*L+l)*1024 + h*64 + d.
// =====================================================================
#define ATT_L 2048
#define ATT_C3 3072

__device__ __forceinline__ float dot64(const float* qf, const u16* krow) {
    const uint4* k4 = (const uint4*)krow;
    float d = 0.f;
#pragma unroll
    for (int i = 0; i < 8; i++) {
        uint4 kv = k4[i];
        d = fmaf(qf[8 * i + 0], bflo(kv.x), d);
        d = fmaf(qf[8 * i + 1], bfhi(kv.x), d);
        d = fmaf(qf[8 * i + 2], bflo(kv.y), d);
        d = fmaf(qf[8 * i + 3], bfhi(kv.y), d);
        d = fmaf(qf[8 * i + 4], bflo(kv.z), d);
        d = fmaf(qf[8 * i + 5], bfhi(kv.z), d);
        d = fmaf(qf[8 * i + 6], bflo(kv.w), d);
        d = fmaf(qf[8 * i + 7], bfhi(kv.w), d);
    }
    return d;
}

__global__ __launch_bounds__(256) void swa_kernel(
    const u16* __restrict__ qkv, const int* __restrict__ mask,
    u16* __restrict__ values)
{
    __shared__ float wts[4][65];

    const int lane = threadIdx.x & 63;
    const int wv   = threadIdx.x >> 6;
    const int w    = blockIdx.x * 4 + wv;        // global wave id
    const int q    = w & (ATT_L - 1);            // adjacent waves -> adjacent q
    const int h    = (w >> 11) & 15;
    const int b    = w >> 15;
    const size_t base_bl = (size_t)b * ATT_L;
    const int* mrow = mask + b * ATT_L;

    // broadcast-load the query vector (same addresses across all lanes)
    float qf[64];
    {
        const uint4* q4 = (const uint4*)(qkv + (base_bl + q) * ATT_C3 + h * 192);
#pragma unroll
        for (int i = 0; i < 8; i++) {
            uint4 qv = q4[i];
            qf[8 * i + 0] = bflo(qv.x); qf[8 * i + 1] = bfhi(qv.x);
            qf[8 * i + 2] = bflo(qv.y); qf[8 * i + 3] = bfhi(qv.y);
            qf[8 * i + 4] = bflo(qv.z); qf[8 * i + 5] = bfhi(qv.z);
            qf[8 * i + 6] = bflo(qv.w); qf[8 * i + 7] = bfhi(qv.w);
        }
    }

    // lane p: score for pos = q-32+p; lane 0 also covers p=64 (pos=q+32)
    const int pos = q - 32 + lane;
    float s = NEG_SCORE * 0.125f;
    if (pos >= 0 && pos < ATT_L && mrow[pos] != 0)
        s = dot64(qf, qkv + (base_bl + pos) * ATT_C3 + h * 192 + 64) * 0.125f;

    float s2 = -3.0e38f;
    if (lane == 0) {
        const int pos2 = q + 32;
        s2 = NEG_SCORE * 0.125f;
        if (pos2 < ATT_L && mrow[pos2] != 0)
            s2 = dot64(qf, qkv + (base_bl + pos2) * ATT_C3 + h * 192 + 64) * 0.125f;
    }

    // wave max
    float m = fmaxf(s, s2);
#pragma unroll
    for (int off = 1; off < 64; off <<= 1)
        m = fmaxf(m, __shfl_xor(m, off));

    // wave denominator
    float e  = __expf(s - m);
    float e2 = (lane == 0) ? __expf(s2 - m) : 0.f;
    float den = e + e2;
#pragma unroll
    for (int off = 1; off < 64; off <<= 1)
        den += __shfl_xor(den, off);
    const float inv = 1.0f / den;

    wts[wv][lane] = e * inv;
    if (lane == 0) wts[wv][64] = e2 * inv;
    __syncthreads();   // cheap; orders LDS write->read within the block

    // PV: lane d accumulates output dim d; V loads coalesced (128B/wave)
    float acc = 0.f;
    const u16* vbase = qkv + base_bl * ATT_C3 + h * 192 + 128 + lane;
#pragma unroll 4
    for (int p = 0; p < 65; p++) {
        int vpos = q - 32 + p;
        if (vpos < 0 || vpos >= ATT_L) continue;
        float wgt = wts[wv][p];
        float vv  = bflo(vbase[(size_t)vpos * ATT_C3]);
        acc = fmaf(wgt, vv, acc);
    }

    values[(base_bl + q) * 1024 + h * 64 + lane] = f2bf(acc);
}

// =====================================================================
// B=2, L=2048, H=16, hd=64, E=1024, input_dim=1024, window=64 (W=65)
// inputs (fp32 per reference, mask int32):
//   x(4096x1024), padding_mask(2x2048 i32), W_qkv(3072x1024), b_qkv(3072),
//   W_o(1024x1024), b_o(1024).  out: fp32 4096x1024.
// ws layout (48 MB): qkv bf16 24MB | values bf16 8MB | xb 8MB | Wqkvb 6MB | Wob 2MB
// =====================================================================
extern "C" void kernel_launch(void* const* d_in, const int* in_sizes, int n_in,
                              void* d_out, int out_size, void* d_ws, size_t ws_size,
                              hipStream_t stream) {
    const float* x     = (const float*)d_in[0];
    const int*   pmask = (const int*)d_in[1];
    const float* Wqkv  = (const float*)d_in[2];
    const float* bqkv  = (const float*)d_in[3];
    const float* Wo    = (const float*)d_in[4];
    const float* bo    = (const float*)d_in[5];
    float* out = (float*)d_out;

    u16* qkv    = (u16*)d_ws;                          // 4096*3072
    u16* values = qkv    + (size_t)4096 * 3072;        // 4096*1024
    u16* xb     = values + (size_t)4096 * 1024;        // 4096*1024
    u16* Wqkvb  = xb     + (size_t)4096 * 1024;        // 3072*1024
    u16* Wob    = Wqkvb  + (size_t)3072 * 1024;        // 1024*1024

    // 0) convert fp32 inputs to bf16 (2% absmax threshold >> bf16 rounding)
    f32_to_bf16_kernel<<<4096 * 1024 / (256 * 8), 256, 0, stream>>>(x, xb);
    f32_to_bf16_kernel<<<3072 * 1024 / (256 * 8), 256, 0, stream>>>(Wqkv, Wqkvb);
    f32_to_bf16_kernel<<<1024 * 1024 / (256 * 8), 256, 0, stream>>>(Wo, Wob);

    // 1) qkv = x @ Wqkv^T + bqkv : M=4096 N=3072 K=1024 (bf16 out)
    gemm_bt_bias<true><<<dim3(3072 / 128, 4096 / 128), 256, 0, stream>>>(
        xb, Wqkvb, bqkv, qkv, 4096, 3072, 1024);

    // 2) sliding-window attention -> values (bf16), one wave per (b,h,q)
    swa_kernel<<<dim3(2 * 16 * 2048 / 4), 256, 0, stream>>>(qkv, pmask, values);

    // 3) out = values @ Wo^T + bo : M=4096 N=1024 K=1024 (fp32 out)
    gemm_bt_bias<false><<<dim3(1024 / 128, 4096 / 128), 256, 0, stream>>>(
        values, Wob, bo, out, 4096, 1024, 1024);
}

// Round 4
// 174.656 us; speedup vs baseline: 2.5346x; 2.5346x over previous
//
#include <hip/hip_runtime.h>
#include <hip/hip_bf16.h>

typedef unsigned int u32;
typedef unsigned short u16;
typedef __attribute__((ext_vector_type(8))) short short8;   // 8 bf16 (4 VGPRs), MFMA A/B frag
typedef __attribute__((ext_vector_type(4))) float f32x4;    // MFMA C/D frag

#define NEG_SCORE (-100000.0f)

// ---------- bf16 helpers (raw u16 representation) ----------
__device__ __forceinline__ float bflo(u32 u) { return __uint_as_float(u << 16); }
__device__ __forceinline__ float bfhi(u32 u) { return __uint_as_float(u & 0xffff0000u); }
__device__ __forceinline__ u16 f2bf(float f) {
    u32 u = __float_as_uint(f);
    u32 r = (u + 0x7fffu + ((u >> 16) & 1u)) >> 16;   // round-to-nearest-even
    return (u16)r;
}

// ---------- async global->LDS 16B copy ----------
__device__ __forceinline__ void async16(const u16* g, u16* l) {
    __builtin_amdgcn_global_load_lds(
        (const __attribute__((address_space(1))) u32*)g,
        (__attribute__((address_space(3))) u32*)l,
        16, 0, 0);
}

// =====================================================================
// fp32 -> bf16 bulk convert. Each thread converts 8 elements (n % 8 == 0).
// =====================================================================
__global__ __launch_bounds__(256) void f32_to_bf16_kernel(
    const float* __restrict__ src, u16* __restrict__ dst)
{
    const int i = blockIdx.x * 256 + threadIdx.x;
    const float4* s4 = (const float4*)src;
    float4 a = s4[2 * i + 0];
    float4 b = s4[2 * i + 1];
    uint4 o;
    o.x = (u32)f2bf(a.x) | ((u32)f2bf(a.y) << 16);
    o.y = (u32)f2bf(a.z) | ((u32)f2bf(a.w) << 16);
    o.z = (u32)f2bf(b.x) | ((u32)f2bf(b.y) << 16);
    o.w = (u32)f2bf(b.z) | ((u32)f2bf(b.w) << 16);
    ((uint4*)dst)[i] = o;
}

// =====================================================================
// GEMM: C(M,N) = A(M,K) * Bt(N,K)^T + bias(N); bf16 A/B, fp32 bias/accum.
// OUT_BF16 selects bf16 or fp32 C. Requires M%128==0, N%128==0, K%32==0.
// m97-style: 128x128 tile, BK=32, 256 threads = 4 waves, each wave 64x64.
// =====================================================================
template <bool OUT_BF16>
__global__ __launch_bounds__(256) void gemm_bt_bias(
    const u16* __restrict__ A, const u16* __restrict__ Bt,
    const float* __restrict__ bias, void* __restrict__ Cv,
    int M, int N, int K)
{
    __shared__ u16 sA[128 * 32];   // 8 KB, row-major 128 rows x 32 cols
    __shared__ u16 sB[128 * 32];

    const int t    = threadIdx.x;
    const int m0   = blockIdx.y * 128;
    const int n0   = blockIdx.x * 128;
    const int lane = t & 63;
    const int wv   = t >> 6;
    const int wm   = (wv & 1) * 64;
    const int wn   = (wv >> 1) * 64;
    const int lr   = lane & 15;
    const int quad = lane >> 4;

    const u16* pa = A  + (size_t)(m0 + (t >> 2)) * K + ((t & 3) << 3);
    const u16* pb = Bt + (size_t)(n0 + (t >> 2)) * K + ((t & 3) << 3);
    u16* la = &sA[t * 8];
    u16* lb = &sB[t * 8];
    const size_t half = (size_t)64 * K;

    const f32x4 zero4 = {0.f, 0.f, 0.f, 0.f};
    f32x4 acc[4][4];
#pragma unroll
    for (int mt = 0; mt < 4; mt++)
#pragma unroll
        for (int nt = 0; nt < 4; nt++) acc[mt][nt] = zero4;

    for (int kk = 0; kk < K; kk += 32) {
        async16(pa + kk, la);
        async16(pa + kk + half, la + 2048);
        async16(pb + kk, lb);
        async16(pb + kk + half, lb + 2048);
        __syncthreads();   // compiler drains vmcnt before s_barrier

        short8 af[4], bfr[4];
#pragma unroll
        for (int mt = 0; mt < 4; mt++)
            af[mt] = *(const short8*)&sA[(wm + mt * 16 + lr) * 32 + quad * 8];
#pragma unroll
        for (int nt = 0; nt < 4; nt++)
            bfr[nt] = *(const short8*)&sB[(wn + nt * 16 + lr) * 32 + quad * 8];

#pragma unroll
        for (int mt = 0; mt < 4; mt++)
#pragma unroll
            for (int nt = 0; nt < 4; nt++)
                acc[mt][nt] = __builtin_amdgcn_mfma_f32_16x16x32_bf16(
                    af[mt], bfr[nt], acc[mt][nt], 0, 0, 0);
        __syncthreads();
    }

    float bv[4];
#pragma unroll
    for (int nt = 0; nt < 4; nt++)
        bv[nt] = bias[n0 + wn + nt * 16 + lr];

    // D layout: lane holds D[m = quad*4+i][n = lane&15] for i=0..3
#pragma unroll
    for (int mt = 0; mt < 4; mt++) {
#pragma unroll
        for (int i = 0; i < 4; i++) {
            size_t row = (size_t)(m0 + wm + mt * 16 + quad * 4 + i);
#pragma unroll
            for (int nt = 0; nt < 4; nt++) {
                float v = acc[mt][nt][i] + bv[nt];
                size_t idx = row * N + n0 + wn + nt * 16 + lr;
                if (OUT_BF16) ((u16*)Cv)[idx] = f2bf(v);
                else          ((float*)Cv)[idx] = v;
            }
        }
    }
}

// =====================================================================
// MFMA flash-style sliding-window attention.
// One workgroup (256 thr / 4 waves) per (b, h, 64-query tile).
// qkv row (b*L+l)*3072, head h at [h*192, +192): q|k|v 64/64/64.
// Window w=32 each side -> K/V union for a 64-q tile = 128 rows.
//  phase 1: stage Q(64x64), K(128x64), V(128x64), mask(128) to LDS
//  phase 2: S = Q*K^T (each wave: 16 q x 128 pos), mask+softmax in-reg,
//           unnormalized bf16 weights -> sP, 1/den -> sInv
//  phase 3: O^T = V^T * P^T (each wave: 16 dims x 64 q), scale, store.
// LDS tiles use the GEMM-verified chunked layout (32-u16 rows) for all
// b128 frag reads; sV padded to 76 u16/row for the transposed u16 reads.
// =====================================================================
#define ATT_L 2048
#define ATT_C3 3072

__global__ __launch_bounds__(256) void swa_kernel(
    const u16* __restrict__ qkv, const int* __restrict__ mask,
    u16* __restrict__ values)
{
    __shared__ u16 sQ[4096];    // [2 chunks][64 q][32 k]      8 KB
    __shared__ u16 sK[8192];    // [2 chunks][128 pos][32 k]  16 KB
    __shared__ u16 sP[8192];    // [4 chunks][64 q][32 pos]   16 KB
    __shared__ u16 sV[9728];    // [128 pos][76 d] (pad 64->76) 19 KB
    __shared__ int smask[128];
    __shared__ float sInv[64];

    const int t  = threadIdx.x;
    const int q0 = blockIdx.x * 64;
    const int h  = blockIdx.y;
    const int b  = blockIdx.z;
    const size_t base_bl = (size_t)b * ATT_L;
    const int* mrow = mask + b * ATT_L;
    const u16* hbase = qkv + base_bl * ATT_C3 + h * 192;

    // ---------------- phase 1: staging (coalesced 16B units) ----------
#pragma unroll
    for (int rep = 0; rep < 2; rep++) {           // Q: 512 units
        int u = t + rep * 256;
        int r = u >> 3, j = u & 7;
        uint4 d = *(const uint4*)(hbase + (size_t)(q0 + r) * ATT_C3 + j * 8);
        *(uint4*)&sQ[(j >> 2) * 2048 + r * 32 + (j & 3) * 8] = d;
    }
#pragma unroll
    for (int rep = 0; rep < 4; rep++) {           // K: 1024 units (clamped)
        int u = t + rep * 256;
        int r = u >> 3, j = u & 7;
        int pos = q0 - 32 + r;
        int pc = min(max(pos, 0), ATT_L - 1);
        uint4 d = *(const uint4*)(hbase + (size_t)pc * ATT_C3 + 64 + j * 8);
        *(uint4*)&sK[(j >> 2) * 4096 + r * 32 + (j & 3) * 8] = d;
    }
#pragma unroll
    for (int rep = 0; rep < 4; rep++) {           // V: 1024 units (zero OOB)
        int u = t + rep * 256;
        int r = u >> 3, j = u & 7;
        int pos = q0 - 32 + r;
        uint4 d = make_uint4(0, 0, 0, 0);
        if (pos >= 0 && pos < ATT_L)
            d = *(const uint4*)(hbase + (size_t)pos * ATT_C3 + 128 + j * 8);
        *(uint2*)&sV[r * 76 + j * 8]     = make_uint2(d.x, d.y);
        *(uint2*)&sV[r * 76 + j * 8 + 4] = make_uint2(d.z, d.w);
    }
    if (t < 128) {
        int pos = q0 - 32 + t;
        smask[t] = (pos >= 0 && pos < ATT_L) ? mrow[pos] : 0;
    }
    __syncthreads();

    const int lane = t & 63;
    const int wv   = t >> 6;
    const int lr   = lane & 15;
    const int quad = lane >> 4;

    // ---------------- phase 2: S = Q K^T, softmax --------------------
    const int qm0 = wv * 16;   // wave's 16 queries
    short8 aq0 = *(const short8*)&sQ[0 * 2048 + (qm0 + lr) * 32 + quad * 8];
    short8 aq1 = *(const short8*)&sQ[1 * 2048 + (qm0 + lr) * 32 + quad * 8];

    const f32x4 zero4 = {0.f, 0.f, 0.f, 0.f};
    f32x4 acc[8];
#pragma unroll
    for (int nt = 0; nt < 8; nt++) {
        short8 b0 = *(const short8*)&sK[0 * 4096 + (nt * 16 + lr) * 32 + quad * 8];
        short8 b1 = *(const short8*)&sK[1 * 4096 + (nt * 16 + lr) * 32 + quad * 8];
        acc[nt] = __builtin_amdgcn_mfma_f32_16x16x32_bf16(aq0, b0, zero4, 0, 0, 0);
        acc[nt] = __builtin_amdgcn_mfma_f32_16x16x32_bf16(aq1, b1, acc[nt], 0, 0, 0);
    }

    // rows: D[m=quad*4+i][n=lr] per 16x16 tile; row q_t = qm0+quad*4+i,
    // col pos-in-tile nidx = nt*16+lr (global pos = q0-32+nidx)
#pragma unroll
    for (int i = 0; i < 4; i++) {
        const int q_t = qm0 + quad * 4 + i;
        float sc[8];
#pragma unroll
        for (int nt = 0; nt < 8; nt++) {
            int nidx = nt * 16 + lr;
            int woff = nidx - q_t;            // window offset, valid in [0,64]
            float s;
            if ((unsigned)woff > 64u)       s = -1.0e30f;            // outside window
            else if (smask[nidx] == 0)      s = NEG_SCORE * 0.125f;  // masked / OOB
            else                            s = acc[nt][i] * 0.125f;
            sc[nt] = s;
        }
        float mx = sc[0];
#pragma unroll
        for (int nt = 1; nt < 8; nt++) mx = fmaxf(mx, sc[nt]);
#pragma unroll
        for (int off = 1; off < 16; off <<= 1) mx = fmaxf(mx, __shfl_xor(mx, off));

        float den = 0.f;
#pragma unroll
        for (int nt = 0; nt < 8; nt++) {
            int nidx = nt * 16 + lr;
            u16 eb = f2bf(__expf(sc[nt] - mx));
            den += bflo((u32)eb);             // denominator from rounded weights
            sP[(nidx >> 5) * 2048 + q_t * 32 + (nidx & 31)] = eb;
        }
#pragma unroll
        for (int off = 1; off < 16; off <<= 1) den += __shfl_xor(den, off);
        if (lr == 0) sInv[q_t] = 1.0f / den;
    }
    __syncthreads();

    // ---------------- phase 3: O^T = V^T P^T -------------------------
    const int dm0 = wv * 16;   // wave's 16 output dims
    f32x4 acc2[4];
#pragma unroll
    for (int nt = 0; nt < 4; nt++) acc2[nt] = zero4;

#pragma unroll
    for (int c = 0; c < 4; c++) {
        short8 av;
#pragma unroll
        for (int j = 0; j < 8; j++)
            av[j] = (short)sV[(c * 32 + quad * 8 + j) * 76 + dm0 + lr];
#pragma unroll
        for (int nt = 0; nt < 4; nt++) {
            short8 bp = *(const short8*)&sP[c * 2048 + (nt * 16 + lr) * 32 + quad * 8];
            acc2[nt] = __builtin_amdgcn_mfma_f32_16x16x32_bf16(av, bp, acc2[nt], 0, 0, 0);
        }
    }

    // D2[m=dim=quad*4+i][n=query=lr]; write 4 contiguous dims as 8B
#pragma unroll
    for (int nt = 0; nt < 4; nt++) {
        int q_t = nt * 16 + lr;
        float iv = sInv[q_t];
        u32 w0 = (u32)f2bf(acc2[nt][0] * iv) | ((u32)f2bf(acc2[nt][1] * iv) << 16);
        u32 w1 = (u32)f2bf(acc2[nt][2] * iv) | ((u32)f2bf(acc2[nt][3] * iv) << 16);
        *(uint2*)&values[(base_bl + q0 + q_t) * 1024 + h * 64 + dm0 + quad * 4] =
            make_uint2(w0, w1);
    }
}

// =====================================================================
// B=2, L=2048, H=16, hd=64, E=1024, input_dim=1024, window=64 (W=65)
// inputs (fp32 per reference, mask int32):
//   x(4096x1024), padding_mask(2x2048 i32), W_qkv(3072x1024), b_qkv(3072),
//   W_o(1024x1024), b_o(1024).  out: fp32 4096x1024.
// ws layout (48 MB): qkv bf16 24MB | values bf16 8MB | xb 8MB | Wqkvb 6MB | Wob 2MB
// =====================================================================
extern "C" void kernel_launch(void* const* d_in, const int* in_sizes, int n_in,
                              void* d_out, int out_size, void* d_ws, size_t ws_size,
                              hipStream_t stream) {
    const float* x     = (const float*)d_in[0];
    const int*   pmask = (const int*)d_in[1];
    const float* Wqkv  = (const float*)d_in[2];
    const float* bqkv  = (const float*)d_in[3];
    const float* Wo    = (const float*)d_in[4];
    const float* bo    = (const float*)d_in[5];
    float* out = (float*)d_out;

    u16* qkv    = (u16*)d_ws;                          // 4096*3072
    u16* values = qkv    + (size_t)4096 * 3072;        // 4096*1024
    u16* xb     = values + (size_t)4096 * 1024;        // 4096*1024
    u16* Wqkvb  = xb     + (size_t)4096 * 1024;        // 3072*1024
    u16* Wob    = Wqkvb  + (size_t)3072 * 1024;        // 1024*1024

    // 0) convert fp32 inputs to bf16 (2% absmax threshold >> bf16 rounding)
    f32_to_bf16_kernel<<<4096 * 1024 / (256 * 8), 256, 0, stream>>>(x, xb);
    f32_to_bf16_kernel<<<3072 * 1024 / (256 * 8), 256, 0, stream>>>(Wqkv, Wqkvb);
    f32_to_bf16_kernel<<<1024 * 1024 / (256 * 8), 256, 0, stream>>>(Wo, Wob);

    // 1) qkv = x @ Wqkv^T + bqkv : M=4096 N=3072 K=1024 (bf16 out)
    gemm_bt_bias<true><<<dim3(3072 / 128, 4096 / 128), 256, 0, stream>>>(
        xb, Wqkvb, bqkv, qkv, 4096, 3072, 1024);

    // 2) MFMA flash sliding-window attention -> values (bf16)
    swa_kernel<<<dim3(2048 / 64, 16, 2), 256, 0, stream>>>(qkv, pmask, values);

    // 3) out = values @ Wo^T + bo : M=4096 N=1024 K=1024 (fp32 out)
    gemm_bt_bias<false><<<dim3(1024 / 128, 4096 / 128), 256, 0, stream>>>(
        values, Wob, bo, out, 4096, 1024, 1024);
}

// Round 5
// 154.943 us; speedup vs baseline: 2.8571x; 1.1272x over previous
//
#include <hip/hip_runtime.h>
#include <hip/hip_bf16.h>

typedef unsigned int u32;
typedef unsigned short u16;
typedef __attribute__((ext_vector_type(8))) short short8;   // 8 bf16 (4 VGPRs), MFMA A/B frag
typedef __attribute__((ext_vector_type(4))) float f32x4;    // MFMA C/D frag

#define NEG_SCORE (-100000.0f)

// ---------- bf16 helpers (raw u16 representation) ----------
__device__ __forceinline__ float bflo(u32 u) { return __uint_as_float(u << 16); }
__device__ __forceinline__ float bfhi(u32 u) { return __uint_as_float(u & 0xffff0000u); }
__device__ __forceinline__ u16 f2bf(float f) {
    u32 u = __float_as_uint(f);
    u32 r = (u + 0x7fffu + ((u >> 16) & 1u)) >> 16;   // round-to-nearest-even
    return (u16)r;
}

// ---------- async global->LDS 16B copy ----------
__device__ __forceinline__ void async16(const u16* g, u16* l) {
    __builtin_amdgcn_global_load_lds(
        (const __attribute__((address_space(1))) u32*)g,
        (__attribute__((address_space(3))) u32*)l,
        16, 0, 0);
}

// =====================================================================
// Fused fp32 -> bf16 convert for all three inputs (one launch).
// blocks [0,2048): x (4M elems) | [2048,3584): W_qkv (3M) | [3584,4096): W_o (1M)
// Each thread converts 8 elements.
// =====================================================================
__global__ __launch_bounds__(256) void convert_all_kernel(
    const float* __restrict__ x,    u16* __restrict__ xb,
    const float* __restrict__ wqkv, u16* __restrict__ wqkvb,
    const float* __restrict__ wo,   u16* __restrict__ wob)
{
    const int bid = blockIdx.x;
    const float* src; u16* dst; int base;
    if (bid < 2048)      { src = x;    dst = xb;    base = bid; }
    else if (bid < 3584) { src = wqkv; dst = wqkvb; base = bid - 2048; }
    else                 { src = wo;   dst = wob;   base = bid - 3584; }
    const int i = base * 256 + threadIdx.x;
    const float4* s4 = (const float4*)src;
    float4 a = s4[2 * i + 0];
    float4 b = s4[2 * i + 1];
    uint4 o;
    o.x = (u32)f2bf(a.x) | ((u32)f2bf(a.y) << 16);
    o.y = (u32)f2bf(a.z) | ((u32)f2bf(a.w) << 16);
    o.z = (u32)f2bf(b.x) | ((u32)f2bf(b.y) << 16);
    o.w = (u32)f2bf(b.z) | ((u32)f2bf(b.w) << 16);
    ((uint4*)dst)[i] = o;
}

// =====================================================================
// GEMM: C(M,TN*gridX) = A(M,K) * Bt(N,K)^T + bias(N); bf16 A/B, fp32 accum.
// BK=64 (2 chunks of 32 k), 128xTN tile, 256 thr / 4 waves.
//   TN=128: waves 2x2, wave-tile 64x64, acc[4][4]   (GEMM1)
//   TN=64 : waves 2x2, wave-tile 64x32, acc[4][2]   (GEMM2; 2x more blocks)
// LDS chunked layout (32-u16 rows) identical to the verified BK=32 kernel;
// async16 dest = wave base + lane*16B in every staging loop (checked).
// =====================================================================
template <int TN, bool OUT_BF16>
__global__ __launch_bounds__(256) void gemm_bt_bias(
    const u16* __restrict__ A, const u16* __restrict__ Bt,
    const float* __restrict__ bias, void* __restrict__ Cv,
    int M, int N, int K)
{
    constexpr int NT = TN / 32;            // MFMA n-tiles per wave (4 or 2)
    __shared__ u16 sA[2 * 128 * 32];       // 16 KB: [chunk][row][32]
    __shared__ u16 sB[2 * TN * 32];        // 16 or 8 KB

    const int t    = threadIdx.x;
    const int m0   = blockIdx.y * 128;
    const int n0   = blockIdx.x * TN;
    const int lane = t & 63;
    const int wv   = t >> 6;
    const int wm   = (wv & 1) * 64;
    const int wn   = (wv >> 1) * (TN / 2);
    const int lr   = lane & 15;
    const int quad = lane >> 4;

    const int srow = t >> 2;               // 0..63
    const int sj   = (t & 3) * 8;          // col offset in 32-elem chunk

    const f32x4 zero4 = {0.f, 0.f, 0.f, 0.f};
    f32x4 acc[4][NT];
#pragma unroll
    for (int mt = 0; mt < 4; mt++)
#pragma unroll
        for (int nt = 0; nt < NT; nt++) acc[mt][nt] = zero4;

    for (int kk = 0; kk < K; kk += 64) {
        // A: 2 chunks x 128 rows
#pragma unroll
        for (int c = 0; c < 2; c++)
#pragma unroll
            for (int r2 = 0; r2 < 2; r2++) {
                int row = srow + 64 * r2;
                async16(A + (size_t)(m0 + row) * K + kk + c * 32 + sj,
                        &sA[c * 4096 + row * 32 + sj]);
            }
        // B: 2 chunks x TN rows
#pragma unroll
        for (int c = 0; c < 2; c++)
#pragma unroll
            for (int r2 = 0; r2 < TN / 64; r2++) {
                int row = srow + 64 * r2;
                async16(Bt + (size_t)(n0 + row) * K + kk + c * 32 + sj,
                        &sB[c * (TN * 32) + row * 32 + sj]);
            }
        __syncthreads();   // compiler drains vmcnt before s_barrier

#pragma unroll
        for (int ks = 0; ks < 2; ks++) {
            short8 af[4], bfr[NT];
#pragma unroll
            for (int mt = 0; mt < 4; mt++)
                af[mt] = *(const short8*)&sA[ks * 4096 + (wm + mt * 16 + lr) * 32 + quad * 8];
#pragma unroll
            for (int nt = 0; nt < NT; nt++)
                bfr[nt] = *(const short8*)&sB[ks * (TN * 32) + (wn + nt * 16 + lr) * 32 + quad * 8];

#pragma unroll
            for (int mt = 0; mt < 4; mt++)
#pragma unroll
                for (int nt = 0; nt < NT; nt++)
                    acc[mt][nt] = __builtin_amdgcn_mfma_f32_16x16x32_bf16(
                        af[mt], bfr[nt], acc[mt][nt], 0, 0, 0);
        }
        __syncthreads();
    }

    float bv[NT];
#pragma unroll
    for (int nt = 0; nt < NT; nt++)
        bv[nt] = bias[n0 + wn + nt * 16 + lr];

    // D layout: lane holds D[m = quad*4+i][n = lane&15] for i=0..3
#pragma unroll
    for (int mt = 0; mt < 4; mt++) {
#pragma unroll
        for (int i = 0; i < 4; i++) {
            size_t row = (size_t)(m0 + wm + mt * 16 + quad * 4 + i);
#pragma unroll
            for (int nt = 0; nt < NT; nt++) {
                float v = acc[mt][nt][i] + bv[nt];
                size_t idx = row * N + n0 + wn + nt * 16 + lr;
                if (OUT_BF16) ((u16*)Cv)[idx] = f2bf(v);
                else          ((float*)Cv)[idx] = v;
            }
        }
    }
}

// =====================================================================
// MFMA flash-style sliding-window attention (verified round 4).
// One workgroup (256 thr / 4 waves) per (b, h, 64-query tile).
// =====================================================================
#define ATT_L 2048
#define ATT_C3 3072

__global__ __launch_bounds__(256) void swa_kernel(
    const u16* __restrict__ qkv, const int* __restrict__ mask,
    u16* __restrict__ values)
{
    __shared__ u16 sQ[4096];    // [2 chunks][64 q][32 k]      8 KB
    __shared__ u16 sK[8192];    // [2 chunks][128 pos][32 k]  16 KB
    __shared__ u16 sP[8192];    // [4 chunks][64 q][32 pos]   16 KB
    __shared__ u16 sV[9728];    // [128 pos][76 d] (pad 64->76) 19 KB
    __shared__ int smask[128];
    __shared__ float sInv[64];

    const int t  = threadIdx.x;
    const int q0 = blockIdx.x * 64;
    const int h  = blockIdx.y;
    const int b  = blockIdx.z;
    const size_t base_bl = (size_t)b * ATT_L;
    const int* mrow = mask + b * ATT_L;
    const u16* hbase = qkv + base_bl * ATT_C3 + h * 192;

    // ---------------- phase 1: staging (coalesced 16B units) ----------
#pragma unroll
    for (int rep = 0; rep < 2; rep++) {           // Q: 512 units
        int u = t + rep * 256;
        int r = u >> 3, j = u & 7;
        uint4 d = *(const uint4*)(hbase + (size_t)(q0 + r) * ATT_C3 + j * 8);
        *(uint4*)&sQ[(j >> 2) * 2048 + r * 32 + (j & 3) * 8] = d;
    }
#pragma unroll
    for (int rep = 0; rep < 4; rep++) {           // K: 1024 units (clamped)
        int u = t + rep * 256;
        int r = u >> 3, j = u & 7;
        int pos = q0 - 32 + r;
        int pc = min(max(pos, 0), ATT_L - 1);
        uint4 d = *(const uint4*)(hbase + (size_t)pc * ATT_C3 + 64 + j * 8);
        *(uint4*)&sK[(j >> 2) * 4096 + r * 32 + (j & 3) * 8] = d;
    }
#pragma unroll
    for (int rep = 0; rep < 4; rep++) {           // V: 1024 units (zero OOB)
        int u = t + rep * 256;
        int r = u >> 3, j = u & 7;
        int pos = q0 - 32 + r;
        uint4 d = make_uint4(0, 0, 0, 0);
        if (pos >= 0 && pos < ATT_L)
            d = *(const uint4*)(hbase + (size_t)pos * ATT_C3 + 128 + j * 8);
        *(uint2*)&sV[r * 76 + j * 8]     = make_uint2(d.x, d.y);
        *(uint2*)&sV[r * 76 + j * 8 + 4] = make_uint2(d.z, d.w);
    }
    if (t < 128) {
        int pos = q0 - 32 + t;
        smask[t] = (pos >= 0 && pos < ATT_L) ? mrow[pos] : 0;
    }
    __syncthreads();

    const int lane = t & 63;
    const int wv   = t >> 6;
    const int lr   = lane & 15;
    const int quad = lane >> 4;

    // ---------------- phase 2: S = Q K^T, softmax --------------------
    const int qm0 = wv * 16;   // wave's 16 queries
    short8 aq0 = *(const short8*)&sQ[0 * 2048 + (qm0 + lr) * 32 + quad * 8];
    short8 aq1 = *(const short8*)&sQ[1 * 2048 + (qm0 + lr) * 32 + quad * 8];

    const f32x4 zero4 = {0.f, 0.f, 0.f, 0.f};
    f32x4 acc[8];
#pragma unroll
    for (int nt = 0; nt < 8; nt++) {
        short8 b0 = *(const short8*)&sK[0 * 4096 + (nt * 16 + lr) * 32 + quad * 8];
        short8 b1 = *(const short8*)&sK[1 * 4096 + (nt * 16 + lr) * 32 + quad * 8];
        acc[nt] = __builtin_amdgcn_mfma_f32_16x16x32_bf16(aq0, b0, zero4, 0, 0, 0);
        acc[nt] = __builtin_amdgcn_mfma_f32_16x16x32_bf16(aq1, b1, acc[nt], 0, 0, 0);
    }

#pragma unroll
    for (int i = 0; i < 4; i++) {
        const int q_t = qm0 + quad * 4 + i;
        float sc[8];
#pragma unroll
        for (int nt = 0; nt < 8; nt++) {
            int nidx = nt * 16 + lr;
            int woff = nidx - q_t;            // window offset, valid in [0,64]
            float s;
            if ((unsigned)woff > 64u)       s = -1.0e30f;            // outside window
            else if (smask[nidx] == 0)      s = NEG_SCORE * 0.125f;  // masked / OOB
            else                            s = acc[nt][i] * 0.125f;
            sc[nt] = s;
        }
        float mx = sc[0];
#pragma unroll
        for (int nt = 1; nt < 8; nt++) mx = fmaxf(mx, sc[nt]);
#pragma unroll
        for (int off = 1; off < 16; off <<= 1) mx = fmaxf(mx, __shfl_xor(mx, off));

        float den = 0.f;
#pragma unroll
        for (int nt = 0; nt < 8; nt++) {
            int nidx = nt * 16 + lr;
            u16 eb = f2bf(__expf(sc[nt] - mx));
            den += bflo((u32)eb);             // denominator from rounded weights
            sP[(nidx >> 5) * 2048 + q_t * 32 + (nidx & 31)] = eb;
        }
#pragma unroll
        for (int off = 1; off < 16; off <<= 1) den += __shfl_xor(den, off);
        if (lr == 0) sInv[q_t] = 1.0f / den;
    }
    __syncthreads();

    // ---------------- phase 3: O^T = V^T P^T -------------------------
    const int dm0 = wv * 16;   // wave's 16 output dims
    f32x4 acc2[4];
#pragma unroll
    for (int nt = 0; nt < 4; nt++) acc2[nt] = zero4;

#pragma unroll
    for (int c = 0; c < 4; c++) {
        short8 av;
#pragma unroll
        for (int j = 0; j < 8; j++)
            av[j] = (short)sV[(c * 32 + quad * 8 + j) * 76 + dm0 + lr];
#pragma unroll
        for (int nt = 0; nt < 4; nt++) {
            short8 bp = *(const short8*)&sP[c * 2048 + (nt * 16 + lr) * 32 + quad * 8];
            acc2[nt] = __builtin_amdgcn_mfma_f32_16x16x32_bf16(av, bp, acc2[nt], 0, 0, 0);
        }
    }

#pragma unroll
    for (int nt = 0; nt < 4; nt++) {
        int q_t = nt * 16 + lr;
        float iv = sInv[q_t];
        u32 w0 = (u32)f2bf(acc2[nt][0] * iv) | ((u32)f2bf(acc2[nt][1] * iv) << 16);
        u32 w1 = (u32)f2bf(acc2[nt][2] * iv) | ((u32)f2bf(acc2[nt][3] * iv) << 16);
        *(uint2*)&values[(base_bl + q0 + q_t) * 1024 + h * 64 + dm0 + quad * 4] =
            make_uint2(w0, w1);
    }
}

// =====================================================================
// B=2, L=2048, H=16, hd=64, E=1024, input_dim=1024, window=64 (W=65)
// ws layout (48 MB): qkv bf16 24MB | values bf16 8MB | xb 8MB | Wqkvb 6MB | Wob 2MB
// =====================================================================
extern "C" void kernel_launch(void* const* d_in, const int* in_sizes, int n_in,
                              void* d_out, int out_size, void* d_ws, size_t ws_size,
                              hipStream_t stream) {
    const float* x     = (const float*)d_in[0];
    const int*   pmask = (const int*)d_in[1];
    const float* Wqkv  = (const float*)d_in[2];
    const float* bqkv  = (const float*)d_in[3];
    const float* Wo    = (const float*)d_in[4];
    const float* bo    = (const float*)d_in[5];
    float* out = (float*)d_out;

    u16* qkv    = (u16*)d_ws;                          // 4096*3072
    u16* values = qkv    + (size_t)4096 * 3072;        // 4096*1024
    u16* xb     = values + (size_t)4096 * 1024;        // 4096*1024
    u16* Wqkvb  = xb     + (size_t)4096 * 1024;        // 3072*1024
    u16* Wob    = Wqkvb  + (size_t)3072 * 1024;        // 1024*1024

    // 0) fused fp32 -> bf16 converts (one launch)
    convert_all_kernel<<<4096, 256, 0, stream>>>(x, xb, Wqkv, Wqkvb, Wo, Wob);

    // 1) qkv = x @ Wqkv^T + bqkv : M=4096 N=3072 K=1024 (bf16 out), 128x128 tile
    gemm_bt_bias<128, true><<<dim3(3072 / 128, 4096 / 128), 256, 0, stream>>>(
        xb, Wqkvb, bqkv, qkv, 4096, 3072, 1024);

    // 2) MFMA flash sliding-window attention -> values (bf16)
    swa_kernel<<<dim3(2048 / 64, 16, 2), 256, 0, stream>>>(qkv, pmask, values);

    // 3) out = values @ Wo^T + bo : M=4096 N=1024 K=1024 (fp32 out), 128x64 tile
    gemm_bt_bias<64, false><<<dim3(1024 / 64, 4096 / 128), 256, 0, stream>>>(
        values, Wob, bo, out, 4096, 1024, 1024);
}

// Round 6
// 150.628 us; speedup vs baseline: 2.9390x; 1.0287x over previous
//
#include <hip/hip_runtime.h>
#include <hip/hip_bf16.h>

typedef unsigned int u32;
typedef unsigned short u16;
typedef __attribute__((ext_vector_type(8))) short short8;   // 8 bf16 (4 VGPRs), MFMA A/B frag
typedef __attribute__((ext_vector_type(4))) float f32x4;    // MFMA C/D frag

#define NEG_SCORE (-100000.0f)

// ---------- bf16 helpers (raw u16 representation) ----------
__device__ __forceinline__ float bflo(u32 u) { return __uint_as_float(u << 16); }
__device__ __forceinline__ float bfhi(u32 u) { return __uint_as_float(u & 0xffff0000u); }
__device__ __forceinline__ u16 f2bf(float f) {
    u32 u = __float_as_uint(f);
    u32 r = (u + 0x7fffu + ((u >> 16) & 1u)) >> 16;   // round-to-nearest-even
    return (u16)r;
}

// ---------- async global->LDS 16B copy ----------
__device__ __forceinline__ void async16(const u16* g, u16* l) {
    __builtin_amdgcn_global_load_lds(
        (const __attribute__((address_space(1))) u32*)g,
        (__attribute__((address_space(3))) u32*)l,
        16, 0, 0);
}

// =====================================================================
// Fused fp32 -> bf16 convert for all three inputs (one launch).
// blocks [0,2048): x (4M elems) | [2048,3584): W_qkv (3M) | [3584,4096): W_o (1M)
// Each thread converts 8 elements.
// =====================================================================
__global__ __launch_bounds__(256) void convert_all_kernel(
    const float* __restrict__ x,    u16* __restrict__ xb,
    const float* __restrict__ wqkv, u16* __restrict__ wqkvb,
    const float* __restrict__ wo,   u16* __restrict__ wob)
{
    const int bid = blockIdx.x;
    const float* src; u16* dst; int base;
    if (bid < 2048)      { src = x;    dst = xb;    base = bid; }
    else if (bid < 3584) { src = wqkv; dst = wqkvb; base = bid - 2048; }
    else                 { src = wo;   dst = wob;   base = bid - 3584; }
    const int i = base * 256 + threadIdx.x;
    const float4* s4 = (const float4*)src;
    float4 a = s4[2 * i + 0];
    float4 b = s4[2 * i + 1];
    uint4 o;
    o.x = (u32)f2bf(a.x) | ((u32)f2bf(a.y) << 16);
    o.y = (u32)f2bf(a.z) | ((u32)f2bf(a.w) << 16);
    o.z = (u32)f2bf(b.x) | ((u32)f2bf(b.y) << 16);
    o.w = (u32)f2bf(b.z) | ((u32)f2bf(b.w) << 16);
    ((uint4*)dst)[i] = o;
}

// =====================================================================
// GEMM: C(M,TN*gridX) = A(M,K) * Bt(N,K)^T + bias(N); bf16 A/B, fp32 accum.
// BK=64 (2 chunks of 32 k), 128xTN tile, 256 thr / 4 waves.
//   TN=128: waves 2x2, wave-tile 64x64, acc[4][4]   (GEMM1)
//   TN=64 : waves 2x2, wave-tile 64x32, acc[4][2]   (GEMM2; 2x more blocks)
// =====================================================================
template <int TN, bool OUT_BF16>
__global__ __launch_bounds__(256) void gemm_bt_bias(
    const u16* __restrict__ A, const u16* __restrict__ Bt,
    const float* __restrict__ bias, void* __restrict__ Cv,
    int M, int N, int K)
{
    constexpr int NT = TN / 32;            // MFMA n-tiles per wave (4 or 2)
    __shared__ u16 sA[2 * 128 * 32];       // 16 KB: [chunk][row][32]
    __shared__ u16 sB[2 * TN * 32];        // 16 or 8 KB

    const int t    = threadIdx.x;
    const int m0   = blockIdx.y * 128;
    const int n0   = blockIdx.x * TN;
    const int lane = t & 63;
    const int wv   = t >> 6;
    const int wm   = (wv & 1) * 64;
    const int wn   = (wv >> 1) * (TN / 2);
    const int lr   = lane & 15;
    const int quad = lane >> 4;

    const int srow = t >> 2;               // 0..63
    const int sj   = (t & 3) * 8;          // col offset in 32-elem chunk

    const f32x4 zero4 = {0.f, 0.f, 0.f, 0.f};
    f32x4 acc[4][NT];
#pragma unroll
    for (int mt = 0; mt < 4; mt++)
#pragma unroll
        for (int nt = 0; nt < NT; nt++) acc[mt][nt] = zero4;

    for (int kk = 0; kk < K; kk += 64) {
#pragma unroll
        for (int c = 0; c < 2; c++)
#pragma unroll
            for (int r2 = 0; r2 < 2; r2++) {
                int row = srow + 64 * r2;
                async16(A + (size_t)(m0 + row) * K + kk + c * 32 + sj,
                        &sA[c * 4096 + row * 32 + sj]);
            }
#pragma unroll
        for (int c = 0; c < 2; c++)
#pragma unroll
            for (int r2 = 0; r2 < TN / 64; r2++) {
                int row = srow + 64 * r2;
                async16(Bt + (size_t)(n0 + row) * K + kk + c * 32 + sj,
                        &sB[c * (TN * 32) + row * 32 + sj]);
            }
        __syncthreads();   // compiler drains vmcnt before s_barrier

#pragma unroll
        for (int ks = 0; ks < 2; ks++) {
            short8 af[4], bfr[NT];
#pragma unroll
            for (int mt = 0; mt < 4; mt++)
                af[mt] = *(const short8*)&sA[ks * 4096 + (wm + mt * 16 + lr) * 32 + quad * 8];
#pragma unroll
            for (int nt = 0; nt < NT; nt++)
                bfr[nt] = *(const short8*)&sB[ks * (TN * 32) + (wn + nt * 16 + lr) * 32 + quad * 8];

#pragma unroll
            for (int mt = 0; mt < 4; mt++)
#pragma unroll
                for (int nt = 0; nt < NT; nt++)
                    acc[mt][nt] = __builtin_amdgcn_mfma_f32_16x16x32_bf16(
                        af[mt], bfr[nt], acc[mt][nt], 0, 0, 0);
        }
        __syncthreads();
    }

    float bv[NT];
#pragma unroll
    for (int nt = 0; nt < NT; nt++)
        bv[nt] = bias[n0 + wn + nt * 16 + lr];

    // D layout: lane holds D[m = quad*4+i][n = lane&15] for i=0..3
#pragma unroll
    for (int mt = 0; mt < 4; mt++) {
#pragma unroll
        for (int i = 0; i < 4; i++) {
            size_t row = (size_t)(m0 + wm + mt * 16 + quad * 4 + i);
#pragma unroll
            for (int nt = 0; nt < NT; nt++) {
                float v = acc[mt][nt][i] + bv[nt];
                size_t idx = row * N + n0 + wn + nt * 16 + lr;
                if (OUT_BF16) ((u16*)Cv)[idx] = f2bf(v);
                else          ((float*)Cv)[idx] = v;
            }
        }
    }
}

// =====================================================================
// MFMA flash-style sliding-window attention (round-4 verified semantics).
// Round-6 changes: (a) Q A-frags loaded directly from global (no sQ),
// (b) sP overlaid on sK (union buffer sKP) with one extra barrier after
// the QK^T MFMAs. LDS 59 KB -> ~36 KB => 4 blocks/CU (was 2).
// =====================================================================
#define ATT_L 2048
#define ATT_C3 3072

__global__ __launch_bounds__(256) void swa_kernel(
    const u16* __restrict__ qkv, const int* __restrict__ mask,
    u16* __restrict__ values)
{
    // phase 2: K as [2 chunks][128 pos][32 k]; phase 3: P as [4 chunks][64 q][32 pos]
    __shared__ u16 sKP[8192];   // 16 KB
    __shared__ u16 sV[9728];    // [128 pos][76 d] (pad 64->76) 19 KB
    __shared__ int smask[128];
    __shared__ float sInv[64];

    const int t  = threadIdx.x;
    const int q0 = blockIdx.x * 64;
    const int h  = blockIdx.y;
    const int b  = blockIdx.z;
    const size_t base_bl = (size_t)b * ATT_L;
    const int* mrow = mask + b * ATT_L;
    const u16* hbase = qkv + base_bl * ATT_C3 + h * 192;

    // ---------------- phase 1: staging (coalesced 16B units) ----------
#pragma unroll
    for (int rep = 0; rep < 4; rep++) {           // K: 1024 units (clamped)
        int u = t + rep * 256;
        int r = u >> 3, j = u & 7;
        int pos = q0 - 32 + r;
        int pc = min(max(pos, 0), ATT_L - 1);
        uint4 d = *(const uint4*)(hbase + (size_t)pc * ATT_C3 + 64 + j * 8);
        *(uint4*)&sKP[(j >> 2) * 4096 + r * 32 + (j & 3) * 8] = d;
    }
#pragma unroll
    for (int rep = 0; rep < 4; rep++) {           // V: 1024 units (zero OOB)
        int u = t + rep * 256;
        int r = u >> 3, j = u & 7;
        int pos = q0 - 32 + r;
        uint4 d = make_uint4(0, 0, 0, 0);
        if (pos >= 0 && pos < ATT_L)
            d = *(const uint4*)(hbase + (size_t)pos * ATT_C3 + 128 + j * 8);
        *(uint2*)&sV[r * 76 + j * 8]     = make_uint2(d.x, d.y);
        *(uint2*)&sV[r * 76 + j * 8 + 4] = make_uint2(d.z, d.w);
    }
    if (t < 128) {
        int pos = q0 - 32 + t;
        smask[t] = (pos >= 0 && pos < ATT_L) ? mrow[pos] : 0;
    }

    const int lane = t & 63;
    const int wv   = t >> 6;
    const int lr   = lane & 15;
    const int quad = lane >> 4;
    const int qm0  = wv * 16;   // wave's 16 queries

    // Q A-frags direct from global: lane holds A[m=lr][k=quad*8+j]
    const u16* qrow = hbase + (size_t)(q0 + qm0 + lr) * ATT_C3 + quad * 8;
    short8 aq0 = *(const short8*)qrow;          // k = quad*8 .. +8
    short8 aq1 = *(const short8*)(qrow + 32);   // k = 32 + quad*8 .. +8

    __syncthreads();

    // ---------------- phase 2: S = Q K^T ----------------------------
    const f32x4 zero4 = {0.f, 0.f, 0.f, 0.f};
    f32x4 acc[8];
#pragma unroll
    for (int nt = 0; nt < 8; nt++) {
        short8 b0 = *(const short8*)&sKP[0 * 4096 + (nt * 16 + lr) * 32 + quad * 8];
        short8 b1 = *(const short8*)&sKP[1 * 4096 + (nt * 16 + lr) * 32 + quad * 8];
        acc[nt] = __builtin_amdgcn_mfma_f32_16x16x32_bf16(aq0, b0, zero4, 0, 0, 0);
        acc[nt] = __builtin_amdgcn_mfma_f32_16x16x32_bf16(aq1, b1, acc[nt], 0, 0, 0);
    }
    __syncthreads();   // all sKP (K) reads done before P overwrites it

    // ---------------- softmax, unnormalized bf16 weights -> sKP(P) ---
#pragma unroll
    for (int i = 0; i < 4; i++) {
        const int q_t = qm0 + quad * 4 + i;
        float sc[8];
#pragma unroll
        for (int nt = 0; nt < 8; nt++) {
            int nidx = nt * 16 + lr;
            int woff = nidx - q_t;            // window offset, valid in [0,64]
            float s;
            if ((unsigned)woff > 64u)       s = -1.0e30f;            // outside window
            else if (smask[nidx] == 0)      s = NEG_SCORE * 0.125f;  // masked / OOB
            else                            s = acc[nt][i] * 0.125f;
            sc[nt] = s;
        }
        float mx = sc[0];
#pragma unroll
        for (int nt = 1; nt < 8; nt++) mx = fmaxf(mx, sc[nt]);
#pragma unroll
        for (int off = 1; off < 16; off <<= 1) mx = fmaxf(mx, __shfl_xor(mx, off));

        float den = 0.f;
#pragma unroll
        for (int nt = 0; nt < 8; nt++) {
            int nidx = nt * 16 + lr;
            u16 eb = f2bf(__expf(sc[nt] - mx));
            den += bflo((u32)eb);             // denominator from rounded weights
            sKP[(nidx >> 5) * 2048 + q_t * 32 + (nidx & 31)] = eb;
        }
#pragma unroll
        for (int off = 1; off < 16; off <<= 1) den += __shfl_xor(den, off);
        if (lr == 0) sInv[q_t] = 1.0f / den;
    }
    __syncthreads();

    // ---------------- phase 3: O^T = V^T P^T -------------------------
    const int dm0 = wv * 16;   // wave's 16 output dims
    f32x4 acc2[4];
#pragma unroll
    for (int nt = 0; nt < 4; nt++) acc2[nt] = zero4;

#pragma unroll
    for (int c = 0; c < 4; c++) {
        short8 av;
#pragma unroll
        for (int j = 0; j < 8; j++)
            av[j] = (short)sV[(c * 32 + quad * 8 + j) * 76 + dm0 + lr];
#pragma unroll
        for (int nt = 0; nt < 4; nt++) {
            short8 bp = *(const short8*)&sKP[c * 2048 + (nt * 16 + lr) * 32 + quad * 8];
            acc2[nt] = __builtin_amdgcn_mfma_f32_16x16x32_bf16(av, bp, acc2[nt], 0, 0, 0);
        }
    }

#pragma unroll
    for (int nt = 0; nt < 4; nt++) {
        int q_t = nt * 16 + lr;
        float iv = sInv[q_t];
        u32 w0 = (u32)f2bf(acc2[nt][0] * iv) | ((u32)f2bf(acc2[nt][1] * iv) << 16);
        u32 w1 = (u32)f2bf(acc2[nt][2] * iv) | ((u32)f2bf(acc2[nt][3] * iv) << 16);
        *(uint2*)&values[(base_bl + q0 + q_t) * 1024 + h * 64 + dm0 + quad * 4] =
            make_uint2(w0, w1);
    }
}

// =====================================================================
// B=2, L=2048, H=16, hd=64, E=1024, input_dim=1024, window=64 (W=65)
// ws layout (48 MB): qkv bf16 24MB | values bf16 8MB | xb 8MB | Wqkvb 6MB | Wob 2MB
// =====================================================================
extern "C" void kernel_launch(void* const* d_in, const int* in_sizes, int n_in,
                              void* d_out, int out_size, void* d_ws, size_t ws_size,
                              hipStream_t stream) {
    const float* x     = (const float*)d_in[0];
    const int*   pmask = (const int*)d_in[1];
    const float* Wqkv  = (const float*)d_in[2];
    const float* bqkv  = (const float*)d_in[3];
    const float* Wo    = (const float*)d_in[4];
    const float* bo    = (const float*)d_in[5];
    float* out = (float*)d_out;

    u16* qkv    = (u16*)d_ws;                          // 4096*3072
    u16* values = qkv    + (size_t)4096 * 3072;        // 4096*1024
    u16* xb     = values + (size_t)4096 * 1024;        // 4096*1024
    u16* Wqkvb  = xb     + (size_t)4096 * 1024;        // 3072*1024
    u16* Wob    = Wqkvb  + (size_t)3072 * 1024;        // 1024*1024

    // 0) fused fp32 -> bf16 converts (one launch)
    convert_all_kernel<<<4096, 256, 0, stream>>>(x, xb, Wqkv, Wqkvb, Wo, Wob);

    // 1) qkv = x @ Wqkv^T + bqkv : M=4096 N=3072 K=1024 (bf16 out), 128x128 tile
    gemm_bt_bias<128, true><<<dim3(3072 / 128, 4096 / 128), 256, 0, stream>>>(
        xb, Wqkvb, bqkv, qkv, 4096, 3072, 1024);

    // 2) MFMA flash sliding-window attention -> values (bf16)
    swa_kernel<<<dim3(2048 / 64, 16, 2), 256, 0, stream>>>(qkv, pmask, values);

    // 3) out = values @ Wo^T + bo : M=4096 N=1024 K=1024 (fp32 out), 128x64 tile
    gemm_bt_bias<64, false><<<dim3(1024 / 64, 4096 / 128), 256, 0, stream>>>(
        values, Wob, bo, out, 4096, 1024, 1024);
}